// Round 6
// baseline (261.898 us; speedup 1.0000x reference)
//
#include <hip/hip_runtime.h>
#include <math.h>

#define D  32
#define BN 16384
#define PP 16

typedef __bf16 bf16x8 __attribute__((ext_vector_type(8)));
typedef __bf16 bf16x4 __attribute__((ext_vector_type(4)));
typedef float  floatx4 __attribute__((ext_vector_type(4)));

#define K1 1.44269504088896341f      // log2(e)
#define K2 2.88539008177792681f      // 2*log2(e)

// LDS image (per hop): Whh + T0t + TRt, all [128 rows][32 cols] bf16 with
// ROW STRIDE 80 B (verified 2-way-free banking). Wu is GONE: step-0's
// Wu@u is precomputed per (hop,fb) into GU (bf16, global) and enters as
// the MFMA C-operand. acc-init on the MATRIX pipe via one-hot B:
//   step 0 : acc = T0t @ onehot(k0) + GU[fb]          (T0t carries bias)
//   step>=1: acc = TRt @ onehot(j) + T0t @ onehot(k) + Whh @ h
// LDS = 30720 image + 10240 H = 40960 -> exactly 4 blocks/CU (160 KiB).
#define WHH_OFF    0
#define T0T_OFF    10240
#define TRT_OFF    20480
#define IMG_BYTES  30720
#define H_OFF      30720
#define LDS_BYTES  (IMG_BYTES + 8 * 1280)  // H: 4 waves x 2 chains x 16 x 80B

__device__ __forceinline__ float sigf(float x) {
    float e = __builtin_amdgcn_exp2f(-x * K1);
    return __builtin_amdgcn_rcpf(1.0f + e);
}
__device__ __forceinline__ float logsigf(float x) {
    float ax = fabsf(x);
    float l = log1pf(__expf(-ax));
    return (x >= 0.0f) ? -l : x - l;
}
__device__ __forceinline__ floatx4 cvt4(bf16x4 v) {
    floatx4 r = { (float)v[0], (float)v[1], (float)v[2], (float)v[3] };
    return r;
}

// One-hot B-fragment: lane (q,bnl) holds B[k=q*8+j][col=bnl] = (q*8+j==sel).
__device__ __forceinline__ bf16x8 onehot8(int sel, int q) {
    union { unsigned w[4]; bf16x8 v; } u;
    const unsigned val = 0x3F80u << ((sel & 1) * 16);
    const int grp = sel >> 1;                 // element-pair index 0..15
    #pragma unroll
    for (int wd = 0; wd < 4; ++wd)
        u.w[wd] = (grp == q * 4 + wd) ? val : 0u;
    return u.v;
}

// ---------------------------------------------------------------------------
// ids [0,8192)            : Whh images (bf16, per hop)
// ids [8192,16384)        : T0t (2 x 128 g x 32 k, bias folded in)
// ids [16384,24576)       : TRt (2 x 128 g x 32 j)
// ids [24576,1073152)     : GU  (2 x 16384 fb x 32 gq) = Wih[:,0:32]@u, bf16
// ids [1073152,1597440)   : pidx (2 x 16384 fb x 16 p, 5-bit-packed int)
__global__ __launch_bounds__(256)
void prep_tables(const float* __restrict__ user_table,
                 const float* __restrict__ ent, const float* __restrict__ rel,
                 const float* __restrict__ wih0, const float* __restrict__ whh0,
                 const float* __restrict__ bih0, const float* __restrict__ bhh0,
                 const float* __restrict__ wih1, const float* __restrict__ whh1,
                 const float* __restrict__ bih1, const float* __restrict__ bhh1,
                 const int* __restrict__ users, const int* __restrict__ items,
                 const int* __restrict__ lp0, const int* __restrict__ lp1,
                 char* __restrict__ imgs, __bf16* __restrict__ GU,
                 int* __restrict__ pidx)
{
    const int id = blockIdx.x * 256 + threadIdx.x;
    if (id < 8192) {                             // Whh image
        const int hop  = id >> 12;
        const int e    = id & 4095;
        const int gate = e >> 5, d = e & 31;
        float v = (hop ? whh1 : whh0)[(size_t)gate * 32 + d];
        ((__bf16*)(imgs + hop * IMG_BYTES + WHH_OFF))[gate * 40 + d] = (__bf16)v;
    } else if (id < 16384) {                     // T0t = bias + We@ent
        const int idb = id - 8192;
        const int hop = idb >> 12;
        const int g   = (idb >> 5) & 127;
        const int k   = idb & 31;
        const float* wih = hop ? wih1 : wih0;
        const float4* w4 = (const float4*)(wih + (size_t)g * 64 + 32);
        const float4* e4 = (const float4*)(ent + (size_t)k * 32);
        float a = hop ? bih1[g] + bhh1[g] : bih0[g] + bhh0[g];
        #pragma unroll
        for (int i = 0; i < 8; ++i) {
            float4 w = w4[i], x = e4[i];
            a = fmaf(w.x, x.x, a); a = fmaf(w.y, x.y, a);
            a = fmaf(w.z, x.z, a); a = fmaf(w.w, x.w, a);
        }
        ((__bf16*)(imgs + hop * IMG_BYTES + T0T_OFF))[g * 40 + k] = (__bf16)a;
    } else if (id < 24576) {                     // TRt = Wr@rel (no bias)
        const int idb = id - 16384;
        const int hop = idb >> 12;
        const int g   = (idb >> 5) & 127;
        const int j   = idb & 31;
        const float* wih = hop ? wih1 : wih0;
        const float4* w4 = (const float4*)(wih + (size_t)g * 64);
        const float4* r4 = (const float4*)(rel + (size_t)j * 32);
        float a = 0.0f;
        #pragma unroll
        for (int i = 0; i < 8; ++i) {
            float4 w = w4[i], x = r4[i];
            a = fmaf(w.x, x.x, a); a = fmaf(w.y, x.y, a);
            a = fmaf(w.z, x.z, a); a = fmaf(w.w, x.w, a);
        }
        ((__bf16*)(imgs + hop * IMG_BYTES + TRT_OFF))[g * 40 + j] = (__bf16)a;
    } else if (id < 1073152) {                   // GU = Wih[:,0:32]@u (bf16)
        const int c   = id - 24576;
        const int hop = c >> 19;
        const int gq  = (c >> 14) & 31;          // wave-uniform -> w broadcast
        const int fb  = c & 16383;
        const float* wih = hop ? wih1 : wih0;
        const float4* u4 = (const float4*)(user_table + (size_t)users[fb] * 32);
        float4 uu[8];
        #pragma unroll
        for (int i = 0; i < 8; ++i) uu[i] = u4[i];
        __bf16 r[4];
        #pragma unroll
        for (int t = 0; t < 4; ++t) {
            const float4* w4 = (const float4*)(wih + (size_t)(gq * 4 + t) * 64);
            float a = 0.0f;
            #pragma unroll
            for (int i = 0; i < 8; ++i) {
                float4 w = w4[i];
                a = fmaf(w.x, uu[i].x, a); a = fmaf(w.y, uu[i].y, a);
                a = fmaf(w.z, uu[i].z, a); a = fmaf(w.w, uu[i].w, a);
            }
            r[t] = (__bf16)a;
        }
        bf16x4 v = { r[0], r[1], r[2], r[3] };
        *(bf16x4*)(GU + ((size_t)(hop * BN + fb) * 128 + gq * 4)) = v;
    } else if (id < 1597440) {                   // pidx: pack 5 x 5-bit rows
        const int c   = id - 1073152;
        const int hop = c >> 18;
        const int rem = c & 262143;
        const int fb  = rem >> 4;
        const int p   = rem & 15;
        const int item = items[fb];
        int w;
        if (hop == 0) {
            const int* il = lp0 + ((size_t)item * PP + p) * 3;
            w = il[0] | (il[1] << 5) | (il[2] << 10);
        } else {
            const int* il = lp1 + ((size_t)item * PP + p) * 5;
            w = il[0] | (il[1] << 5) | (il[2] << 10) | (il[3] << 15)
                      | (il[4] << 20);
        }
        pidx[(size_t)(hop * BN + fb) * PP + p] = w;
    }
}

// nonlin in C-layout D[gate][pair]: lane (q=lane>>4, p=lane&15), tile mt holds
// gates 16mt+4q+r of pair p. H rows are 80 B (verified stride).
template<bool FIRST, bool LAST>
__device__ __forceinline__ void nonlin(
    floatx4* __restrict__ acc, float* __restrict__ cst,
    float* __restrict__ hlo, float* __restrict__ hhi,
    char* __restrict__ Hw, int q, int bnl)
{
    #pragma unroll
    for (int hf = 0; hf < 2; ++hf) {
        float* hout = hf ? hhi : hlo;
        #pragma unroll
        for (int r = 0; r < 4; ++r) {
            float gi = acc[0 + hf][r], gf = acc[2 + hf][r],
                  gg = acc[4 + hf][r], go = acc[6 + hf][r];
            float Ai = 1.0f + __builtin_amdgcn_exp2f(-gi * K1);
            float Af = 1.0f + __builtin_amdgcn_exp2f(-gf * K1);
            float G2 = __builtin_amdgcn_exp2f(gg * K2);
            float Gp = G2 + 1.0f, Gm = G2 - 1.0f;
            float cold = FIRST ? 0.0f : cst[hf * 4 + r];
            float num = cold * Ai * Gp + Gm * Af;
            float c = num * __builtin_amdgcn_rcpf(Af * Ai * Gp);
            cst[hf * 4 + r] = c;
            float Ao = 1.0f + __builtin_amdgcn_exp2f(-go * K1);
            float C2 = __builtin_amdgcn_exp2f(c * K2);
            hout[r] = (C2 - 1.0f) * __builtin_amdgcn_rcpf(Ao * (C2 + 1.0f));
        }
    }
    if (!LAST) {
        bf16x4 plo = { (__bf16)hlo[0], (__bf16)hlo[1], (__bf16)hlo[2], (__bf16)hlo[3] };
        bf16x4 phi = { (__bf16)hhi[0], (__bf16)hhi[1], (__bf16)hhi[2], (__bf16)hhi[3] };
        *(bf16x4*)(Hw + bnl * 80 + 8 * q)      = plo;
        *(bf16x4*)(Hw + bnl * 80 + 32 + 8 * q) = phi;
    }
}

// Grid 4096: hop = bid&1, idx = bid>>1. 4 waves x 2 chains. Per step per
// chain per tile: 2-3 MFMAs (one-hot selects + Whh), step-0 C-init from GU.
// No scattered loads in the chain loop. LDS 40960 -> 4 blocks/CU.
__global__ __launch_bounds__(256, 4)
void hop_mfma(const int*   __restrict__ pidx,
              const char*  __restrict__ imgs,
              const __bf16* __restrict__ GU,
              float* __restrict__ F0,            // (B,32) sum_p h
              float* __restrict__ F1)
{
    __shared__ __align__(16) char lds[LDS_BYTES];

    const bool second = blockIdx.x & 1;
    const int  idx    = blockIdx.x >> 1;
    const int tid  = threadIdx.x;
    const int lane = tid & 63;
    const int wave = tid >> 6;
    const int q    = lane >> 4;
    const int bnl  = lane & 15;

    // ---- per-chain loads first (overlap with image copy) -------------------
    const int fbA = idx * 8 + wave;
    const int fbB = fbA + 4;
    const int hbase = second ? BN : 0;
    const int ixA = pidx[(size_t)(hbase + fbA) * PP + bnl];
    const int ixB = pidx[(size_t)(hbase + fbB) * PP + bnl];
    bf16x4 guhA[8], guhB[8];
    #pragma unroll
    for (int mt = 0; mt < 8; ++mt) {
        guhA[mt] = *(const bf16x4*)(GU + ((size_t)(hbase + fbA) * 128 + mt * 16 + q * 4));
        guhB[mt] = *(const bf16x4*)(GU + ((size_t)(hbase + fbB) * 128 + mt * 16 + q * 4));
    }

    // ---- image -> LDS: 1920 float4 -----------------------------------------
    {
        const float4* g4 = (const float4*)(imgs + (second ? IMG_BYTES : 0));
        float4* l4 = (float4*)lds;
        #pragma unroll
        for (int i = 0; i < 8; ++i) {
            int k = i * 256 + tid;
            if (k < IMG_BYTES / 16) l4[k] = g4[k];
        }
    }
    const char* Whh = lds + WHH_OFF;
    const char* T0t = lds + T0T_OFF;
    const char* TRt = lds + TRT_OFF;
    char* HwA = lds + H_OFF + (wave * 2 + 0) * 1280;
    char* HwB = lds + H_OFF + (wave * 2 + 1) * 1280;

    __syncthreads();   // image ready

    float cstA[8], cstB[8], hloA[4], hhiA[4], hloB[4], hhiB[4];
    const floatx4 zf4 = { 0.0f, 0.0f, 0.0f, 0.0f };

    // ---- step 0: acc = T0t@onehot(k0) + GU ---------------------------------
    {
        bf16x8 ohA = onehot8(ixA & 31, q);
        bf16x8 ohB = onehot8(ixB & 31, q);
        floatx4 accA[8], accB[8];
        #pragma unroll
        for (int mt = 0; mt < 8; ++mt) {
            const int ro = (16 * mt + bnl) * 80 + q * 16;
            bf16x8 t0f = *(const bf16x8*)(T0t + ro);
            accA[mt] = __builtin_amdgcn_mfma_f32_16x16x32_bf16(t0f, ohA, cvt4(guhA[mt]), 0, 0, 0);
            accB[mt] = __builtin_amdgcn_mfma_f32_16x16x32_bf16(t0f, ohB, cvt4(guhB[mt]), 0, 0, 0);
        }
        nonlin<true, false>(accA, cstA, hloA, hhiA, HwA, q, bnl);
        nonlin<true, false>(accB, cstB, hloB, hhiB, HwB, q, bnl);
    }

    // ---- step 1: acc = TRt@onehot(j1) + T0t@onehot(k1) + Whh@h -------------
    {
        bf16x8 ohjA = onehot8((ixA >> 5) & 31, q);
        bf16x8 ohkA = onehot8((ixA >> 10) & 31, q);
        bf16x8 ohjB = onehot8((ixB >> 5) & 31, q);
        bf16x8 ohkB = onehot8((ixB >> 10) & 31, q);
        bf16x8 bhA = *(const bf16x8*)(HwA + bnl * 80 + q * 16);
        bf16x8 bhB = *(const bf16x8*)(HwB + bnl * 80 + q * 16);
        floatx4 accA[8], accB[8];
        #pragma unroll
        for (int mt = 0; mt < 8; ++mt) {
            const int ro = (16 * mt + bnl) * 80 + q * 16;
            bf16x8 trf = *(const bf16x8*)(TRt + ro);
            bf16x8 t0f = *(const bf16x8*)(T0t + ro);
            bf16x8 whf = *(const bf16x8*)(Whh + ro);
            accA[mt] = __builtin_amdgcn_mfma_f32_16x16x32_bf16(trf, ohjA, zf4, 0, 0, 0);
            accB[mt] = __builtin_amdgcn_mfma_f32_16x16x32_bf16(trf, ohjB, zf4, 0, 0, 0);
            accA[mt] = __builtin_amdgcn_mfma_f32_16x16x32_bf16(t0f, ohkA, accA[mt], 0, 0, 0);
            accB[mt] = __builtin_amdgcn_mfma_f32_16x16x32_bf16(t0f, ohkB, accB[mt], 0, 0, 0);
            accA[mt] = __builtin_amdgcn_mfma_f32_16x16x32_bf16(whf, bhA, accA[mt], 0, 0, 0);
            accB[mt] = __builtin_amdgcn_mfma_f32_16x16x32_bf16(whf, bhB, accB[mt], 0, 0, 0);
        }
        if (second) {
            nonlin<false, false>(accA, cstA, hloA, hhiA, HwA, q, bnl);
            nonlin<false, false>(accB, cstB, hloB, hhiB, HwB, q, bnl);
        } else {
            nonlin<false, true>(accA, cstA, hloA, hhiA, HwA, q, bnl);
            nonlin<false, true>(accB, cstB, hloB, hhiB, HwB, q, bnl);
        }
    }

    // ---- step 2 (hop 1 only) -----------------------------------------------
    if (second) {
        bf16x8 ohjA = onehot8((ixA >> 15) & 31, q);
        bf16x8 ohkA = onehot8((ixA >> 20) & 31, q);
        bf16x8 ohjB = onehot8((ixB >> 15) & 31, q);
        bf16x8 ohkB = onehot8((ixB >> 20) & 31, q);
        bf16x8 bhA = *(const bf16x8*)(HwA + bnl * 80 + q * 16);
        bf16x8 bhB = *(const bf16x8*)(HwB + bnl * 80 + q * 16);
        floatx4 accA[8], accB[8];
        #pragma unroll
        for (int mt = 0; mt < 8; ++mt) {
            const int ro = (16 * mt + bnl) * 80 + q * 16;
            bf16x8 trf = *(const bf16x8*)(TRt + ro);
            bf16x8 t0f = *(const bf16x8*)(T0t + ro);
            bf16x8 whf = *(const bf16x8*)(Whh + ro);
            accA[mt] = __builtin_amdgcn_mfma_f32_16x16x32_bf16(trf, ohjA, zf4, 0, 0, 0);
            accB[mt] = __builtin_amdgcn_mfma_f32_16x16x32_bf16(trf, ohjB, zf4, 0, 0, 0);
            accA[mt] = __builtin_amdgcn_mfma_f32_16x16x32_bf16(t0f, ohkA, accA[mt], 0, 0, 0);
            accB[mt] = __builtin_amdgcn_mfma_f32_16x16x32_bf16(t0f, ohkB, accB[mt], 0, 0, 0);
            accA[mt] = __builtin_amdgcn_mfma_f32_16x16x32_bf16(whf, bhA, accA[mt], 0, 0, 0);
            accB[mt] = __builtin_amdgcn_mfma_f32_16x16x32_bf16(whf, bhB, accB[mt], 0, 0, 0);
        }
        nonlin<false, true>(accA, cstA, hloA, hhiA, HwA, q, bnl);
        nonlin<false, true>(accB, cstB, hloB, hhiB, HwB, q, bnl);
    }

    // ---- sum over pairs (reduce across bnl lanes), write F -----------------
    #pragma unroll
    for (int r = 0; r < 4; ++r) {
        #pragma unroll
        for (int m = 1; m < 16; m <<= 1) {
            hloA[r] += __shfl_xor(hloA[r], m);
            hhiA[r] += __shfl_xor(hhiA[r], m);
            hloB[r] += __shfl_xor(hloB[r], m);
            hhiB[r] += __shfl_xor(hhiB[r], m);
        }
    }
    if (bnl == 0) {
        float* Fout = (second ? F1 : F0);
        float4 vloA = { hloA[0], hloA[1], hloA[2], hloA[3] };
        float4 vhiA = { hhiA[0], hhiA[1], hhiA[2], hhiA[3] };
        float4 vloB = { hloB[0], hloB[1], hloB[2], hloB[3] };
        float4 vhiB = { hhiB[0], hhiB[1], hhiB[2], hhiB[3] };
        *(float4*)(Fout + (size_t)fbA * D + 4 * q)      = vloA;
        *(float4*)(Fout + (size_t)fbA * D + 16 + 4 * q) = vhiA;
        *(float4*)(Fout + (size_t)fbB * D + 4 * q)      = vloB;
        *(float4*)(Fout + (size_t)fbB * D + 16 + 4 * q) = vhiB;
    }
}

// Per b: emb0=(ent[items]+F0)@W^T+b ; emb1=(emb0+F1)@W^T+b ; score=dot(u,emb1)
__global__ __launch_bounds__(256)
void chain_score(const float* __restrict__ user_table,
                 const float* __restrict__ ent_table,
                 const float* __restrict__ agg_w,
                 const float* __restrict__ agg_b,
                 const int*   __restrict__ users,
                 const int*   __restrict__ items,
                 const int*   __restrict__ ratings,
                 const float* __restrict__ F0,
                 const float* __restrict__ F1,
                 float* __restrict__ out,
                 float* __restrict__ partials)
{
    __shared__ float s[8][33];
    __shared__ float red[8];
    const int tid = threadIdx.x;
    const int bb  = tid >> 5;
    const int j   = tid & 31;
    const int b   = blockIdx.x * 8 + bb;
    const int it  = items[b];

    s[bb][j] = ent_table[(size_t)it * D + j] + F0[(size_t)b * D + j];
    __syncthreads();
    const float* __restrict__ w = agg_w + (size_t)j * D;
    float e0 = agg_b[j];
    #pragma unroll
    for (int k = 0; k < D; ++k) e0 = fmaf(s[bb][k], w[k], e0);
    __syncthreads();
    s[bb][j] = e0 + F1[(size_t)b * D + j];
    __syncthreads();
    float e1 = agg_b[j];
    #pragma unroll
    for (int k = 0; k < D; ++k) e1 = fmaf(s[bb][k], w[k], e1);

    float prod = user_table[(size_t)users[b] * D + j] * e1;
    #pragma unroll
    for (int m = 1; m < 32; m <<= 1) prod += __shfl_xor(prod, m);
    if (j == 0) {
        out[1 + b]      = sigf(prod);
        out[1 + BN + b] = (float)it;
        float r = (float)ratings[b];
        red[bb] = r * logsigf(prod) + (1.0f - r) * logsigf(-prod);
    }
    __syncthreads();
    if (tid == 0) {
        float t = 0.0f;
        #pragma unroll
        for (int qq = 0; qq < 8; ++qq) t += red[qq];
        partials[blockIdx.x] = t;
    }
}

__global__ __launch_bounds__(256)
void loss_kernel(const float* __restrict__ partials, float* __restrict__ out)
{
    __shared__ float red[4];
    const int t = threadIdx.x;
    float v = 0.0f;
    #pragma unroll
    for (int qq = 0; qq < 8; ++qq) v += partials[qq * 256 + t];
    #pragma unroll
    for (int m = 1; m < 64; m <<= 1) v += __shfl_xor(v, m);
    if ((t & 63) == 0) red[t >> 6] = v;
    __syncthreads();
    if (t == 0) out[0] = -(red[0] + red[1] + red[2] + red[3]) / (float)BN;
}

extern "C" void kernel_launch(void* const* d_in, const int* in_sizes, int n_in,
                              void* d_out, int out_size, void* d_ws, size_t ws_size,
                              hipStream_t stream)
{
    const float* user_table = (const float*)d_in[0];
    const float* ent_table  = (const float*)d_in[1];
    const float* rel_table  = (const float*)d_in[2];
    const float* w_ih0 = (const float*)d_in[3];
    const float* w_hh0 = (const float*)d_in[4];
    const float* b_ih0 = (const float*)d_in[5];
    const float* b_hh0 = (const float*)d_in[6];
    const float* w_ih1 = (const float*)d_in[7];
    const float* w_hh1 = (const float*)d_in[8];
    const float* b_ih1 = (const float*)d_in[9];
    const float* b_hh1 = (const float*)d_in[10];
    const float* agg_w = (const float*)d_in[11];
    const float* agg_b = (const float*)d_in[12];
    const int* users   = (const int*)d_in[13];
    const int* items   = (const int*)d_in[14];
    const int* ratings = (const int*)d_in[15];
    const int* lp0     = (const int*)d_in[16];
    const int* lp1     = (const int*)d_in[17];
    float* out = (float*)d_out;

    float* ws       = (float*)d_ws;
    float* F0       = ws;                               // BN*32 floats
    float* F1       = F0 + (size_t)BN * D;              // BN*32 floats
    float* partials = F1 + (size_t)BN * D;              // 2048 floats
    char*  imgs     = (char*)(partials + 2048);         // 2 x 30720 B
    int*   pidx     = (int*)(imgs + 2 * IMG_BYTES);     // 2*BN*16 ints (2 MB)
    __bf16* GU      = (__bf16*)(pidx + 2 * (size_t)BN * PP);  // 8 MB

    prep_tables<<<6240, 256, 0, stream>>>(user_table, ent_table, rel_table,
        w_ih0, w_hh0, b_ih0, b_hh0, w_ih1, w_hh1, b_ih1, b_hh1,
        users, items, lp0, lp1, imgs, GU, pidx);
    hop_mfma<<<4096, 256, 0, stream>>>(pidx, imgs, GU, F0, F1);
    chain_score<<<BN / 8, 256, 0, stream>>>(
        user_table, ent_table, agg_w, agg_b, users, items, ratings,
        F0, F1, out, partials);
    loss_kernel<<<1, 256, 0, stream>>>(partials, out);
}